// Round 1
// baseline (364.117 us; speedup 1.0000x reference)
//
#include <hip/hip_runtime.h>

// NeuralFM forward, MI355X.
// Shapes: BATCH=16384, NFIELDS=50, HIDDEN=64, L1=128, L2=64.
// Strategy: 1 wave (64 lanes) handles RPW=8 rows; lane = hidden dim.
//  - gather phase: 50 coalesced 256B emb-row loads per row, accumulate
//    sum / sum-of-squares in registers (never materialize [B,F,D]).
//  - FM vector -> LDS, tiny MLP with W1/W2 streamed once per 8 rows
//    (weights 64KB, L1/L2-hot; amortized 8x).
//  - epilogue: h2 . Wp + first-order bias gather, wave shuffle-reduce.

#define NFIELDS 50
#define HIDDEN  64
#define L1N     128
#define L2N     64
#define RPW     8                 // rows per wave
#define WAVES   4                 // waves per block
#define ROWS_PER_BLOCK (RPW * WAVES)

__global__ __launch_bounds__(256, 2) void neuralfm_kernel(
    const int*   __restrict__ features,   // [B, 50]
    const float* __restrict__ emb,        // [1e6, 64]
    const float* __restrict__ bias_t,     // [1e6, 1]
    const float* __restrict__ w_bias,     // [1,1]
    const float* __restrict__ W1,         // [64, 128]
    const float* __restrict__ b1,         // [128]
    const float* __restrict__ W2,         // [128, 64]
    const float* __restrict__ b2,         // [64]
    const float* __restrict__ Wp,         // [64, 1]
    const float* __restrict__ bp,         // [1]
    float*       __restrict__ out)        // [B, 1]
{
    __shared__ int   sIdx[WAVES][RPW * NFIELDS];
    __shared__ float sFm [WAVES][RPW * HIDDEN];
    __shared__ float sH1 [WAVES][RPW * L1N];

    const int tid  = threadIdx.x;
    const int wave = tid >> 6;
    const int lane = tid & 63;
    const int row0 = blockIdx.x * ROWS_PER_BLOCK + wave * RPW;

    // ---- phase 0: cooperative, coalesced index load (400 contiguous ints) ----
    const int idx_base = row0 * NFIELDS;
    #pragma unroll
    for (int t = lane; t < RPW * NFIELDS; t += 64)
        sIdx[wave][t] = features[idx_base + t];
    __syncthreads();

    // ---- phase 1: embedding gather + FM pooling (lane = dim) ----
    float sum[RPW], sq[RPW];
    #pragma unroll
    for (int r = 0; r < RPW; ++r) { sum[r] = 0.f; sq[r] = 0.f; }

    for (int f = 0; f < NFIELDS; ++f) {
        #pragma unroll
        for (int r = 0; r < RPW; ++r) {
            const int   idx = sIdx[wave][r * NFIELDS + f];   // LDS broadcast
            const float v   = emb[(size_t)idx * HIDDEN + lane]; // coalesced 256B row
            sum[r] += v;
            sq[r]  += v * v;
        }
    }
    #pragma unroll
    for (int r = 0; r < RPW; ++r)
        sFm[wave][r * HIDDEN + lane] = 0.5f * (sum[r] * sum[r] - sq[r]);
    __syncthreads();

    // ---- phase 2: h1 = relu(fm @ W1 + b1); lane owns outputs {lane, lane+64} ----
    float h1a[RPW], h1b[RPW];
    #pragma unroll
    for (int r = 0; r < RPW; ++r) { h1a[r] = 0.f; h1b[r] = 0.f; }

    for (int d = 0; d < HIDDEN; ++d) {
        const float w0 = W1[d * L1N + lane];        // coalesced, L1/L2-hot
        const float w1 = W1[d * L1N + 64 + lane];
        #pragma unroll
        for (int r = 0; r < RPW; ++r) {
            const float fv = sFm[wave][r * HIDDEN + d];  // broadcast
            h1a[r] += fv * w0;
            h1b[r] += fv * w1;
        }
    }
    const float bias1a = b1[lane];
    const float bias1b = b1[64 + lane];
    #pragma unroll
    for (int r = 0; r < RPW; ++r) {
        sH1[wave][r * L1N + lane]      = fmaxf(h1a[r] + bias1a, 0.f);
        sH1[wave][r * L1N + 64 + lane] = fmaxf(h1b[r] + bias1b, 0.f);
    }
    __syncthreads();

    // ---- phase 3: h2 = relu(h1 @ W2 + b2); lane owns output `lane` ----
    float h2[RPW];
    #pragma unroll
    for (int r = 0; r < RPW; ++r) h2[r] = 0.f;

    for (int j = 0; j < L1N; ++j) {
        const float w = W2[j * L2N + lane];         // coalesced, L1/L2-hot
        #pragma unroll
        for (int r = 0; r < RPW; ++r)
            h2[r] += sH1[wave][r * L1N + j] * w;    // broadcast
    }
    const float bias2 = b2[lane];
    const float wp    = Wp[lane];

    float tot[RPW];
    #pragma unroll
    for (int r = 0; r < RPW; ++r)
        tot[r] = fmaxf(h2[r] + bias2, 0.f) * wp;    // partial of h2 . Wp

    // ---- phase 4: first-order bias gather (lanes 0..49, one field each) ----
    if (lane < NFIELDS) {
        #pragma unroll
        for (int r = 0; r < RPW; ++r)
            tot[r] += bias_t[sIdx[wave][r * NFIELDS + lane]];
    }

    // ---- phase 5: wave reduce (pred + feature_bias), add global terms, store ----
    #pragma unroll
    for (int r = 0; r < RPW; ++r) {
        float v = tot[r];
        #pragma unroll
        for (int off = 32; off > 0; off >>= 1)
            v += __shfl_xor(v, off, 64);
        tot[r] = v;
    }
    if (lane == 0) {
        const float c = bp[0] + w_bias[0];
        #pragma unroll
        for (int r = 0; r < RPW; ++r)
            out[row0 + r] = tot[r] + c;
    }
}

extern "C" void kernel_launch(void* const* d_in, const int* in_sizes, int n_in,
                              void* d_out, int out_size, void* d_ws, size_t ws_size,
                              hipStream_t stream) {
    const int*   features = (const int*)  d_in[0];
    // d_in[1] = labels (only shape used in reference; values unused)
    const float* emb      = (const float*)d_in[2];
    const float* bias_t   = (const float*)d_in[3];
    const float* w_bias   = (const float*)d_in[4];
    const float* W1       = (const float*)d_in[5];
    const float* b1       = (const float*)d_in[6];
    const float* W2       = (const float*)d_in[7];
    const float* b2       = (const float*)d_in[8];
    const float* Wp       = (const float*)d_in[9];
    const float* bp       = (const float*)d_in[10];
    float*       out      = (float*)d_out;

    const int batch  = in_sizes[0] / NFIELDS;       // 16384
    const int blocks = batch / ROWS_PER_BLOCK;      // 512

    neuralfm_kernel<<<blocks, 256, 0, stream>>>(
        features, emb, bias_t, w_bias, W1, b1, W2, b2, Wp, bp, out);
}

// Round 2
// 354.465 us; speedup vs baseline: 1.0272x; 1.0272x over previous
//
#include <hip/hip_runtime.h>

// NeuralFM forward, MI355X (gfx950).
// B=16384, F=50, D=64, L1=128, L2=64.
// R2: float4 gather (4 rows/wave-instr, 1KB/instr), 1024 blocks x 256
// (4 blocks/CU, 16 waves/CU), b128 LDS broadcasts in MLP, early bias gather.

#define NFIELDS 50
#define HIDDEN  64
#define L1N     128
#define L2N     64
#define RPW     4                  // rows per wave
#define WAVES   4                  // waves per block
#define ROWS_PER_BLOCK (RPW * WAVES)   // 16

__global__ __launch_bounds__(256, 4) void neuralfm_kernel(
    const int*   __restrict__ features,   // [B, 50]
    const float* __restrict__ emb,        // [1e6, 64]
    const float* __restrict__ bias_t,     // [1e6]
    const float* __restrict__ w_bias,     // [1]
    const float* __restrict__ W1,         // [64, 128]
    const float* __restrict__ b1,         // [128]
    const float* __restrict__ W2,         // [128, 64]
    const float* __restrict__ b2,         // [64]
    const float* __restrict__ Wp,         // [64]
    const float* __restrict__ bp,         // [1]
    float*       __restrict__ out)        // [B]
{
    __shared__ int    sIdx[WAVES][RPW * NFIELDS];        // 3.2 KB
    __shared__ float4 sFm4[WAVES][RPW * HIDDEN / 4];     // 4 KB
    __shared__ float  sH1 [WAVES][RPW * L1N];            // 8 KB

    const int tid  = threadIdx.x;
    const int wave = tid >> 6;
    const int lane = tid & 63;
    const int sub  = lane >> 4;        // which of 4 rows this lane serves
    const int le   = lane & 15;        // dim-quad within the row
    const int row0 = blockIdx.x * ROWS_PER_BLOCK + wave * RPW;

    // ---- phase 0: coalesced index load (200 contiguous ints per wave) ----
    const int idx_base = row0 * NFIELDS;
    #pragma unroll
    for (int t = lane; t < RPW * NFIELDS; t += 64)
        sIdx[wave][t] = features[idx_base + t];
    __syncthreads();

    // ---- early first-order bias gather: latency hides under gather+MLP ----
    float biasacc[RPW];
    #pragma unroll
    for (int r = 0; r < RPW; ++r) biasacc[r] = 0.f;
    if (lane < NFIELDS) {
        #pragma unroll
        for (int r = 0; r < RPW; ++r)
            biasacc[r] = bias_t[sIdx[wave][r * NFIELDS + lane]];
    }

    // ---- phase 1: float4 embedding gather + FM pooling ----
    // one wave-instruction = 4 rows x 256 B = 1 KB
    const float4* __restrict__ emb4 = (const float4*)emb;
    float sx = 0.f, sy = 0.f, sz = 0.f, sw = 0.f;   // sum
    float qx = 0.f, qy = 0.f, qz = 0.f, qw = 0.f;   // sum of squares
    const int* myIdx = &sIdx[wave][sub * NFIELDS];
    #pragma unroll
    for (int f = 0; f < NFIELDS; ++f) {
        const int    idx = myIdx[f];                       // LDS broadcast (16 lanes)
        const float4 v   = emb4[(size_t)idx * (HIDDEN / 4) + le];
        sx += v.x; sy += v.y; sz += v.z; sw += v.w;
        qx += v.x * v.x; qy += v.y * v.y; qz += v.z * v.z; qw += v.w * v.w;
    }
    float4 fm;
    fm.x = 0.5f * (sx * sx - qx);
    fm.y = 0.5f * (sy * sy - qy);
    fm.z = 0.5f * (sz * sz - qz);
    fm.w = 0.5f * (sw * sw - qw);
    sFm4[wave][sub * (HIDDEN / 4) + le] = fm;
    __syncthreads();

    // ---- phase 2: h1 = relu(fm @ W1 + b1); lane owns outputs {lane, lane+64} ----
    float h1a[RPW], h1b[RPW];
    #pragma unroll
    for (int r = 0; r < RPW; ++r) { h1a[r] = 0.f; h1b[r] = 0.f; }

    for (int dq = 0; dq < HIDDEN / 4; ++dq) {
        float w0[4], w1[4];
        #pragma unroll
        for (int c = 0; c < 4; ++c) {
            w0[c] = W1[(4 * dq + c) * L1N + lane];          // coalesced, L2-hot
            w1[c] = W1[(4 * dq + c) * L1N + 64 + lane];
        }
        #pragma unroll
        for (int r = 0; r < RPW; ++r) {
            const float4 fv = sFm4[wave][r * (HIDDEN / 4) + dq];  // b128 broadcast
            h1a[r] += fv.x * w0[0] + fv.y * w0[1] + fv.z * w0[2] + fv.w * w0[3];
            h1b[r] += fv.x * w1[0] + fv.y * w1[1] + fv.z * w1[2] + fv.w * w1[3];
        }
    }
    const float bias1a = b1[lane];
    const float bias1b = b1[64 + lane];
    #pragma unroll
    for (int r = 0; r < RPW; ++r) {
        sH1[wave][r * L1N + lane]      = fmaxf(h1a[r] + bias1a, 0.f);
        sH1[wave][r * L1N + 64 + lane] = fmaxf(h1b[r] + bias1b, 0.f);
    }
    __syncthreads();

    // ---- phase 3: h2 = relu(h1 @ W2 + b2); lane owns output `lane` ----
    const float4* sH14 = (const float4*)&sH1[wave][0];
    float h2[RPW];
    #pragma unroll
    for (int r = 0; r < RPW; ++r) h2[r] = 0.f;

    for (int jq = 0; jq < L1N / 4; ++jq) {
        float w[4];
        #pragma unroll
        for (int c = 0; c < 4; ++c)
            w[c] = W2[(4 * jq + c) * L2N + lane];           // coalesced, L2-hot
        #pragma unroll
        for (int r = 0; r < RPW; ++r) {
            const float4 hv = sH14[r * (L1N / 4) + jq];     // b128 broadcast
            h2[r] += hv.x * w[0] + hv.y * w[1] + hv.z * w[2] + hv.w * w[3];
        }
    }
    const float bias2 = b2[lane];
    const float wp    = Wp[lane];

    float tot[RPW];
    #pragma unroll
    for (int r = 0; r < RPW; ++r)
        tot[r] = fmaxf(h2[r] + bias2, 0.f) * wp + biasacc[r];

    // ---- phase 4: wave reduce (pred + feature_bias), add global terms, store ----
    #pragma unroll
    for (int r = 0; r < RPW; ++r) {
        float v = tot[r];
        #pragma unroll
        for (int off = 32; off > 0; off >>= 1)
            v += __shfl_xor(v, off, 64);
        tot[r] = v;
    }
    if (lane == 0) {
        const float c = bp[0] + w_bias[0];
        #pragma unroll
        for (int r = 0; r < RPW; ++r)
            out[row0 + r] = tot[r] + c;
    }
}

extern "C" void kernel_launch(void* const* d_in, const int* in_sizes, int n_in,
                              void* d_out, int out_size, void* d_ws, size_t ws_size,
                              hipStream_t stream) {
    const int*   features = (const int*)  d_in[0];
    // d_in[1] = labels (values unused by the forward pass)
    const float* emb      = (const float*)d_in[2];
    const float* bias_t   = (const float*)d_in[3];
    const float* w_bias   = (const float*)d_in[4];
    const float* W1       = (const float*)d_in[5];
    const float* b1       = (const float*)d_in[6];
    const float* W2       = (const float*)d_in[7];
    const float* b2       = (const float*)d_in[8];
    const float* Wp       = (const float*)d_in[9];
    const float* bp       = (const float*)d_in[10];
    float*       out      = (float*)d_out;

    const int batch  = in_sizes[0] / NFIELDS;        // 16384
    const int blocks = batch / ROWS_PER_BLOCK;       // 1024

    neuralfm_kernel<<<blocks, 256, 0, stream>>>(
        features, emb, bias_t, w_bias, W1, b1, W2, b2, Wp, bp, out);
}